// Round 4
// baseline (332.314 us; speedup 1.0000x reference)
//
#include <hip/hip_runtime.h>
#include <hip/hip_cooperative_groups.h>
#include <math.h>
#include <string.h>

namespace cg = cooperative_groups;

#define N 12288
#define QP 7168           // padded compact count = 56*128 (E[M]=6144, +18 sigma)
#define TILE 128          // candidates per split (LDS tile)
#define NSPLIT 56         // QP / TILE
#define ACCS 2            // queries per thread
#define QBLK 512          // queries per block
#define NQB 14            // QP / QBLK
#define NBLK (NQB * NSPLIT) // 784 blocks total (also the nn grid)
#define BPB 12            // builder blocks (each owns 1024 indices)
#define NPART (QP / 256)  // 28 loss blocks

typedef unsigned long long ull;

struct CMat { float c[6][6]; };

// ---------------------------------------------------------------------------
// Single fused cooperative kernel. 784 blocks x 256 threads, 4 phases split
// by grid.sync() (runtime-managed barriers: no workspace handshake state, so
// the harness's workspace poison cannot fake a "done" flag).
//
// Phase 1 (blocks 0..11): order-preserving compaction of inside points.
//   Block b owns indices [b*1024,(b+1)*1024) in 4 sub-rounds of 256; the
//   ordering key (b, r*4 + w4, lane) equals ascending original index —
//   bit-identical to the previous build kernels. Global write base computed
//   redundantly per block (recount sdf of blocks [0,b)). Block 11 stores M
//   and sentinel-pads pts[M..QP). Blocks 12..39 init best[] = ~0.
// Phase 2 (all blocks): NN. Block f -> (qb = f%14, s = f/14): queries
//   [qb*512,+512) (2/thread) vs candidate split s in LDS. d' = sqj - 2*dot
//   via the same fma chain (z,y,x). Cross-split combine via device-scope
//   u64 atomicMin (monotone-key<<32 | compact idx: min is order-independent,
//   idx unique => winner identical to sequential min; ties -> smallest j).
//   Blocks fully in the sentinel pad (>= M) skip work (but still sync).
// Phase 3 (blocks 0..27): per-query NN lookup + strain quadratic form +
//   block partials (identical arithmetic and reduction order).
// Phase 4 (block 0): exact 28-partial shuffle-tree finalize -> out.
// ---------------------------------------------------------------------------
template<bool CAREFUL>
__device__ __forceinline__ void nn_inner(
    const float4* __restrict__ tile,
    const float* wx, const float* wy, const float* wz,
    const int* kx,
    float* bd, int* bk)
{
    #pragma unroll 8
    for (int k = 0; k < TILE; ++k) {
        const float4 b = tile[k];
        #pragma unroll
        for (int a = 0; a < ACCS; ++a) {
            float t = fmaf(wz[a], b.z, b.w);
            t = fmaf(wy[a], b.y, t);
            t = fmaf(wx[a], b.x, t);
            bool ok = t < bd[a];
            if (CAREFUL) ok = ok && (k != kx[a]);
            if (ok) { bd[a] = t; bk[a] = k; }
        }
    }
}

__global__ __launch_bounds__(256, 4) void fused_kernel(
    const float* __restrict__ new_xyz,
    const float* __restrict__ xyz,
    const float* __restrict__ gt_sdf,
    float4* __restrict__ pts,
    int* __restrict__ cj,
    int* __restrict__ Mptr,
    ull* __restrict__ best,
    double* __restrict__ partial_sum,
    unsigned int* __restrict__ partial_cnt,
    float* __restrict__ out,
    CMat C)
{
    const int tid = threadIdx.x;
    const int f = blockIdx.x;        // 0..783
    const int lane = tid & 63;
    const int w4 = tid >> 6;         // wave within block, 0..3
    cg::grid_group grid = cg::this_grid();

    // shared memory (union of all phases; 2.2 KB)
    __shared__ float4 tile[TILE];
    __shared__ int wpre[4];
    __shared__ int wcnt[16];
    __shared__ int woff[16];
    __shared__ int tot_s;
    __shared__ double wsum[4];
    __shared__ unsigned wcnt2[4];

    // ======================= Phase 1: build / init ==========================
    if (f < BPB) {
        const int b = f;
        // global prefix: #inside in [0, b*1024), redundant per block
        int cpre = 0;
        for (int rr = 0; rr < b; ++rr) {       // block-uniform trip count
            #pragma unroll
            for (int r = 0; r < 4; ++r)
                cpre += (gt_sdf[rr * 1024 + r * 256 + tid] < 1e-8f) ? 1 : 0;
        }
        #pragma unroll
        for (int off = 32; off > 0; off >>= 1)
            cpre += __shfl_down(cpre, off, 64);  // lane0: wave partial

        // own 1024 indices in 4 sub-rounds; old-wave id = r*4 + w4
        float px[4], py[4], pz[4];
        unsigned insf = 0;
        ull mball[4];
        int rank[4];
        #pragma unroll
        for (int r = 0; r < 4; ++r) {
            const int idx = b * 1024 + r * 256 + tid;
            px[r] = new_xyz[3 * idx + 0];
            py[r] = new_xyz[3 * idx + 1];
            pz[r] = new_xyz[3 * idx + 2];
            const bool ins = gt_sdf[idx] < 1e-8f;
            if (ins) insf |= (1u << r);
            mball[r] = __ballot(ins);
            rank[r] = __popcll(mball[r] & ((1ull << lane) - 1ull));
        }

        if (lane == 0) {
            wpre[w4] = cpre;
            #pragma unroll
            for (int r = 0; r < 4; ++r) wcnt[r * 4 + w4] = __popcll(mball[r]);
        }
        __syncthreads();
        if (tid == 0) {
            const int cb = wpre[0] + wpre[1] + wpre[2] + wpre[3];
            int run = cb;
            for (int w = 0; w < 16; ++w) { woff[w] = run; run += wcnt[w]; }
            tot_s = run;                       // for b==11 this is M
        }
        __syncthreads();

        #pragma unroll
        for (int r = 0; r < 4; ++r) {
            const int slot = woff[r * 4 + w4] + rank[r];
            if (((insf >> r) & 1u) && slot < QP) {
                pts[slot] = make_float4(-2.0f * px[r], -2.0f * py[r], -2.0f * pz[r],
                                        px[r] * px[r] + py[r] * py[r] + pz[r] * pz[r]);
                cj[slot] = b * 1024 + r * 256 + tid;
            }
        }

        if (b == BPB - 1) {
            const int M = tot_s;
            if (tid == 0) *Mptr = M;
            for (int s2 = M + tid; s2 < QP; s2 += 256)
                pts[s2] = make_float4(0.0f, 0.0f, 0.0f, 3e30f);
        }
    } else if (f < BPB + NPART) {
        best[(f - BPB) * 256 + tid] = ~0ull;   // 28*256 = 7168 slots
    }

    grid.sync();

    // ============================ Phase 2: NN ===============================
    {
        const int qb = f % NQB;
        const int s = f / NQB;
        const int qbase = qb * QBLK;
        const int jb = s * TILE;
        const int M = *Mptr;

        if (jb < M && qbase < M) {             // block-uniform guard
            float wx[ACCS], wy[ACCS], wz[ACCS];
            int kx[ACCS];
            #pragma unroll
            for (int a = 0; a < ACCS; ++a) {
                const int ci = qbase + tid + a * 256;
                const float4 q = pts[ci];
                wx[a] = -0.5f * q.x;           // recover raw coords
                wy[a] = -0.5f * q.y;
                wz[a] = -0.5f * q.z;
                kx[a] = ci - jb;               // self position in this split
            }

            if (tid < TILE) tile[tid] = pts[jb + tid];
            __syncthreads();

            float bd[ACCS];
            int bk[ACCS];
            #pragma unroll
            for (int a = 0; a < ACCS; ++a) { bd[a] = 3.0e38f; bk[a] = 0; }

            const bool dirty = (jb < qbase + QBLK) && (jb + TILE > qbase);
            if (dirty)
                nn_inner<true>(tile, wx, wy, wz, kx, bd, bk);
            else
                nn_inner<false>(tile, wx, wy, wz, kx, bd, bk);

            #pragma unroll
            for (int a = 0; a < ACCS; ++a) {
                const int ci = qbase + tid + a * 256;
                unsigned u = __float_as_uint(bd[a]);
                u = ((int)u < 0) ? ~u : (u | 0x80000000u);
                const ull v = ((ull)u << 32) | (ull)(unsigned)(jb + bk[a]);
                atomicMin(&best[ci], v);       // device scope on gfx950
            }
        }
    }

    grid.sync();

    // =========================== Phase 3: loss ==============================
    if (f < NPART) {
        const int ci = f * 256 + tid;
        const ull b64 = best[ci];
        const int M = *Mptr;
        const bool real = (ci < M);

        const unsigned u = (unsigned)(b64 >> 32);
        const unsigned bits = (u & 0x80000000u) ? (u ^ 0x80000000u) : ~u;
        const float key = __uint_as_float(bits);   // min (sqj - 2*dot)
        const int cc = real ? (int)(unsigned)(b64 & 0xffffffffu) : 0;

        const int i  = real ? cj[ci] : 0;
        const int nn = cj[cc];

        const float wix = new_xyz[3 * i + 0];
        const float wiy = new_xyz[3 * i + 1];
        const float wiz = new_xyz[3 * i + 2];
        const float sqi = wix * wix + wiy * wiy + wiz * wiz;

        const float d2 = sqi + key;
        const float nnd = sqrtf(fmaxf(d2, 0.0f));
        const bool valid = real && (nnd > 1e-8f);

        float q = 0.0f;
        if (valid) {
            const float xix = xyz[3 * i + 0], xiy = xyz[3 * i + 1], xiz = xyz[3 * i + 2];
            const float wnx = new_xyz[3 * nn + 0], wny = new_xyz[3 * nn + 1], wnz = new_xyz[3 * nn + 2];
            const float xnx = xyz[3 * nn + 0],     xny = xyz[3 * nn + 1],     xnz = xyz[3 * nn + 2];

            const float du = (wnx - xnx) - (wix - xix);
            const float dv = (wny - xny) - (wiy - xiy);
            const float dw = (wnz - xnz) - (wiz - xiz);
            const float dx = wnx - wix + 1e-8f;
            const float dy = wny - wiy + 1e-8f;
            const float dz = wnz - wiz + 1e-8f;

            float et[6];
            et[0] = du / dx;
            et[1] = dv / dy;
            et[2] = dw / dz;
            et[3] = (du / dy + dv / dx) * 0.5f;
            et[4] = (du / dz + dw / dx) * 0.5f;
            et[5] = (dw / dy + dv / dz) * 0.5f;

            #pragma unroll
            for (int a = 0; a < 6; ++a) {
                float s2 = 0.0f;
                #pragma unroll
                for (int b2 = 0; b2 < 6; ++b2) s2 += C.c[a][b2] * et[b2];
                q += et[a] * s2;
            }
        }

        // block reduction: wave shuffle + LDS handoff (unchanged order)
        double q2 = (double)q * (double)q;
        #pragma unroll
        for (int off = 32; off > 0; off >>= 1)
            q2 += __shfl_down(q2, off, 64);
        const ull vm = __ballot(valid);
        if (lane == 0) { wsum[w4] = q2; wcnt2[w4] = (unsigned)__popcll(vm); }
        __syncthreads();
        if (tid == 0) {
            partial_sum[f] = wsum[0] + wsum[1] + wsum[2] + wsum[3];
            partial_cnt[f] = wcnt2[0] + wcnt2[1] + wcnt2[2] + wcnt2[3];
        }
    }

    grid.sync();

    // ========================= Phase 4: finalize ============================
    if (f == 0 && tid < 64) {
        double s = (tid < NPART) ? partial_sum[tid] : 0.0;
        double c = (tid < NPART) ? (double)partial_cnt[tid] : 0.0;
        #pragma unroll
        for (int off = 32; off > 0; off >>= 1) {
            s += __shfl_down(s, off, 64);
            c += __shfl_down(c, off, 64);
        }
        if (tid == 0) out[0] = (float)(sqrt(s) / c);
    }
}

// ---------------- Host: build C = inv(Ci) -----------------------------------
static void build_cmat(CMat* M)
{
    const double VP = 0.4, EP = 0.21;
    double A[6][12];
    memset(A, 0, sizeof(A));
    double Ci[6][6];
    memset(Ci, 0, sizeof(Ci));
    Ci[0][0] = 1.0 / EP; Ci[0][1] = -VP / EP; Ci[0][2] = -VP / EP;
    Ci[1][0] = -VP / EP; Ci[1][1] = 1.0 / EP; Ci[1][2] = -VP / EP;
    Ci[2][0] = -VP;      Ci[2][1] = -VP;      Ci[2][2] = 1.0 / EP;
    Ci[3][3] = 2.0 * (1.0 + VP) / EP;
    Ci[4][4] = Ci[3][3];
    Ci[5][5] = Ci[3][3];

    for (int i = 0; i < 6; ++i) {
        for (int j = 0; j < 6; ++j) A[i][j] = Ci[i][j];
        A[i][6 + i] = 1.0;
    }
    for (int col = 0; col < 6; ++col) {
        int piv = col;
        for (int r = col + 1; r < 6; ++r)
            if (fabs(A[r][col]) > fabs(A[piv][col])) piv = r;
        if (piv != col)
            for (int c = 0; c < 12; ++c) { double t = A[col][c]; A[col][c] = A[piv][c]; A[piv][c] = t; }
        const double d = A[col][col];
        for (int c = 0; c < 12; ++c) A[col][c] /= d;
        for (int r = 0; r < 6; ++r) {
            if (r == col) continue;
            const double f = A[r][col];
            if (f == 0.0) continue;
            for (int c = 0; c < 12; ++c) A[r][c] -= f * A[col][c];
        }
    }
    for (int i = 0; i < 6; ++i)
        for (int j = 0; j < 6; ++j)
            M->c[i][j] = (float)A[i][6 + j];
}

extern "C" void kernel_launch(void* const* d_in, const int* in_sizes, int n_in,
                              void* d_out, int out_size, void* d_ws, size_t ws_size,
                              hipStream_t stream)
{
    const float* new_xyz = (const float*)d_in[0];
    const float* xyz     = (const float*)d_in[1];
    const float* gt_sdf  = (const float*)d_in[2];
    float* out = (float*)d_out;

    // workspace layout (all consumed slots written before read):
    //   [0,      QP*16) : pts  float4 compacted inside points   (112 KB)
    //   [+,      QP*4)  : cj   original indices                 (28 KB)
    //   [+,      16)    : M    compact count
    //   [+,      QP*8)  : best u64 per-query NN minimum         (56 KB)
    //   then NPART doubles + NPART uints
    char* p = (char*)d_ws;
    float4* pts = (float4*)p;                    p += (size_t)QP * 16;
    int* cj = (int*)p;                           p += (size_t)QP * 4;
    int* Mptr = (int*)p;                         p += 16;
    ull* best = (ull*)p;                         p += (size_t)QP * 8;
    double* partial_sum = (double*)p;            p += NPART * sizeof(double);
    unsigned int* partial_cnt = (unsigned int*)p;

    CMat C;
    build_cmat(&C);

    void* kargs[] = {
        (void*)&new_xyz, (void*)&xyz, (void*)&gt_sdf,
        (void*)&pts, (void*)&cj, (void*)&Mptr, (void*)&best,
        (void*)&partial_sum, (void*)&partial_cnt, (void*)&out, (void*)&C
    };
    hipLaunchCooperativeKernel((void*)fused_kernel, dim3(NBLK), dim3(256),
                               kargs, 0, stream);
}

// Round 5
// 93.855 us; speedup vs baseline: 3.5407x; 3.5407x over previous
//
#include <hip/hip_runtime.h>
#include <math.h>
#include <string.h>

#define N 12288
#define QP 7168           // padded compact count = 56*128 (E[M]=6144, +18 sigma)
#define TILE 128          // candidates per split (LDS tile)
#define NSPLIT 56         // QP / TILE
#define ACCS 2            // queries per thread
#define QBLK 512          // queries per block
#define NQB 14            // QP / QBLK
#define NBLK (NQB * NSPLIT) // 784 nn blocks
#define BT 1024           // build-kernel threads per block
#define BB 12             // build-kernel blocks (N / BT)
#define NPART (QP / 256)  // 28 loss partials

typedef unsigned long long ull;

struct CMat { float c[6][6]; };

// ---------------------------------------------------------------------------
// Kernel 1: order-preserving compaction (round-3 version, unchanged math).
// Block b owns [b*1024,(b+1)*1024); global write base computed redundantly
// (recount sdf of blocks [0,b): block-uniform, L2-broadcast). Ordering key
// (block, wave, lane) == ascending original index. Block 11 stores M and
// sentinel-pads pts. best[]-init spread across grid. ALSO zeroes the two
// ticket counters used by kernel 2 (the dispatch boundary guarantees they
// are 0 before any increment — workspace poison cannot fake them).
// ---------------------------------------------------------------------------
__global__ __launch_bounds__(1024) void build_kernel(
    const float* __restrict__ new_xyz,
    const float* __restrict__ gt_sdf,
    float4* __restrict__ pts,
    int* __restrict__ cj,
    int* __restrict__ Mout,
    ull* __restrict__ best,
    unsigned int* __restrict__ ticket2,
    unsigned int* __restrict__ ticket3)
{
    const int tid = threadIdx.x;
    const int b = blockIdx.x;        // 0..11
    const int lane = tid & 63;
    const int wave = tid >> 6;       // 0..15

    // global prefix: #inside in [0, b*1024), redundant per block
    int cpre = 0;
    #pragma unroll
    for (int r = 0; r < BB - 1; ++r) {
        const float sv = (r < b) ? gt_sdf[r * BT + tid] : 1.0f;
        cpre += (sv < 1e-8f) ? 1 : 0;
    }
    #pragma unroll
    for (int off = 32; off > 0; off >>= 1)
        cpre += __shfl_down(cpre, off, 64);      // lane0: wave partial

    // own range: flags + wave ballot rank
    const int idx = b * BT + tid;
    const float px = new_xyz[3 * idx + 0];
    const float py = new_xyz[3 * idx + 1];
    const float pz = new_xyz[3 * idx + 2];
    const bool ins = gt_sdf[idx] < 1e-8f;
    const ull m = __ballot(ins);
    const int rank = __popcll(m & ((1ull << lane) - 1ull));

    __shared__ int wpre[16];
    __shared__ int wcnt[16];
    __shared__ int woff[16];
    __shared__ int tot_s;
    if (lane == 0) { wpre[wave] = cpre; wcnt[wave] = __popcll(m); }
    __syncthreads();
    if (tid == 0) {
        int cb = 0;
        for (int w = 0; w < 16; ++w) cb += wpre[w];
        int run = cb;
        for (int w = 0; w < 16; ++w) { woff[w] = run; run += wcnt[w]; }
        tot_s = run;
    }
    __syncthreads();

    const int slot = woff[wave] + rank;
    if (ins && slot < QP) {
        pts[slot] = make_float4(-2.0f * px, -2.0f * py, -2.0f * pz,
                                px * px + py * py + pz * pz);
        cj[slot] = idx;
    }

    const int gid = b * BT + tid;
    if (gid < QP) best[gid] = ~0ull;
    if (gid == 0) { *ticket2 = 0u; *ticket3 = 0u; }

    if (b == BB - 1) {
        const int M = tot_s;
        if (tid == 0) *Mout = M;
        for (int s = M + tid; s < QP; s += BT)
            pts[s] = make_float4(0.0f, 0.0f, 0.0f, 3e30f);
    }
}

// ---------------------------------------------------------------------------
// Kernel 2: fused NN + loss. 784 blocks x 256 threads.
// Phase A (all blocks): NN exactly as round 3 — block f -> (qb=f%14, s=f/14),
//   512 queries (2/thread) vs 128-candidate LDS tile, fma chain (z,y,x),
//   device-scope u64 atomicMin into best[ci] (monotone key<<32 | compact idx
//   => winner identical to sequential min, ties -> smallest j).
// Barrier: every block (worker or not) releases ticket2 once its atomics are
//   drained (__syncthreads waits vmcnt(0) -> threadfence -> release add).
// Phase B (blocks 0..27): tid0 acquire-spins until ticket2==784 (s_sleep
//   backoff, bounded -> visible failure not a hang; deadlock-free since only
//   28 spinners hold slots while the other 756 blocks run to completion),
//   then the round-3 loss phase verbatim: per-query lookup + strain form +
//   28-partial reduction + ticket3 last-block finalize. Bit-identical order.
// ---------------------------------------------------------------------------
template<bool CAREFUL>
__device__ __forceinline__ void nn_inner(
    const float4* __restrict__ tile,
    const float* wx, const float* wy, const float* wz,
    const int* kx,
    float* bd, int* bk)
{
    #pragma unroll 8
    for (int k = 0; k < TILE; ++k) {
        const float4 b = tile[k];
        #pragma unroll
        for (int a = 0; a < ACCS; ++a) {
            float t = fmaf(wz[a], b.z, b.w);
            t = fmaf(wy[a], b.y, t);
            t = fmaf(wx[a], b.x, t);
            bool ok = t < bd[a];
            if (CAREFUL) ok = ok && (k != kx[a]);
            if (ok) { bd[a] = t; bk[a] = k; }
        }
    }
}

__global__ __launch_bounds__(256, 4) void nn_loss_kernel(
    const float* __restrict__ new_xyz,
    const float* __restrict__ xyz,
    const float4* __restrict__ pts,
    const int* __restrict__ cj,
    const int* __restrict__ Mptr,
    ull* __restrict__ best,
    unsigned int* __restrict__ ticket2,
    unsigned int* __restrict__ ticket3,
    double* __restrict__ partial_sum,
    unsigned int* __restrict__ partial_cnt,
    float* __restrict__ out,
    CMat C)
{
    const int tid = threadIdx.x;
    const int f = blockIdx.x;        // 0..783
    const int qb = f % NQB;
    const int s = f / NQB;
    const int qbase = qb * QBLK;
    const int jb = s * TILE;
    const int M = *Mptr;

    // ========================= Phase A: NN =================================
    if (jb < M && qbase < M) {               // block-uniform work guard
        float wx[ACCS], wy[ACCS], wz[ACCS];
        int kx[ACCS];
        #pragma unroll
        for (int a = 0; a < ACCS; ++a) {
            const int ci = qbase + tid + a * 256;
            const float4 q = pts[ci];
            wx[a] = -0.5f * q.x;             // recover raw coords
            wy[a] = -0.5f * q.y;
            wz[a] = -0.5f * q.z;
            kx[a] = ci - jb;                 // self position in this split
        }

        __shared__ float4 tile[TILE];
        if (tid < TILE) tile[tid] = pts[jb + tid];
        __syncthreads();

        float bd[ACCS];
        int bk[ACCS];
        #pragma unroll
        for (int a = 0; a < ACCS; ++a) { bd[a] = 3.0e38f; bk[a] = 0; }

        const bool dirty = (jb < qbase + QBLK) && (jb + TILE > qbase);
        if (dirty)
            nn_inner<true>(tile, wx, wy, wz, kx, bd, bk);
        else
            nn_inner<false>(tile, wx, wy, wz, kx, bd, bk);

        #pragma unroll
        for (int a = 0; a < ACCS; ++a) {
            const int ci = qbase + tid + a * 256;
            unsigned u = __float_as_uint(bd[a]);
            u = ((int)u < 0) ? ~u : (u | 0x80000000u);
            const ull v = ((ull)u << 32) | (ull)(unsigned)(jb + bk[a]);
            atomicMin(&best[ci], v);         // device scope on gfx950
        }
    }

    // ==================== barrier: release ticket2 =========================
    __syncthreads();                          // drains this block's atomics
    if (tid == 0) {
        __threadfence();
        __hip_atomic_fetch_add(ticket2, 1u, __ATOMIC_RELEASE,
                               __HIP_MEMORY_SCOPE_AGENT);
    }
    if (f >= NPART) return;                   // 756 blocks done

    // ==================== Phase B: loss (blocks 0..27) =====================
    if (tid == 0) {
        // bounded acquire-spin: all 784 blocks increment unconditionally
        long long guard = 0;
        while (__hip_atomic_load(ticket2, __ATOMIC_ACQUIRE,
                                 __HIP_MEMORY_SCOPE_AGENT) < (unsigned)NBLK) {
            __builtin_amdgcn_s_sleep(8);
            if (++guard > (1ll << 28)) break; // failsafe: wrong > hung
        }
    }
    __syncthreads();

    const int ci = f * 256 + tid;
    const ull b64 = best[ci];
    const bool real = (ci < M);

    const unsigned u = (unsigned)(b64 >> 32);
    const unsigned bits = (u & 0x80000000u) ? (u ^ 0x80000000u) : ~u;
    const float key = __uint_as_float(bits);  // min (sqj - 2*dot)
    const int cc = real ? (int)(unsigned)(b64 & 0xffffffffu) : 0;

    const int i  = real ? cj[ci] : 0;
    const int nn = cj[cc];

    const float wix = new_xyz[3 * i + 0];
    const float wiy = new_xyz[3 * i + 1];
    const float wiz = new_xyz[3 * i + 2];
    const float sqi = wix * wix + wiy * wiy + wiz * wiz;

    const float d2 = sqi + key;
    const float nnd = sqrtf(fmaxf(d2, 0.0f));
    const bool valid = real && (nnd > 1e-8f);

    float q = 0.0f;
    if (valid) {
        const float xix = xyz[3 * i + 0], xiy = xyz[3 * i + 1], xiz = xyz[3 * i + 2];
        const float wnx = new_xyz[3 * nn + 0], wny = new_xyz[3 * nn + 1], wnz = new_xyz[3 * nn + 2];
        const float xnx = xyz[3 * nn + 0],     xny = xyz[3 * nn + 1],     xnz = xyz[3 * nn + 2];

        const float du = (wnx - xnx) - (wix - xix);
        const float dv = (wny - xny) - (wiy - xiy);
        const float dw = (wnz - xnz) - (wiz - xiz);
        const float dx = wnx - wix + 1e-8f;
        const float dy = wny - wiy + 1e-8f;
        const float dz = wnz - wiz + 1e-8f;

        float et[6];
        et[0] = du / dx;
        et[1] = dv / dy;
        et[2] = dw / dz;
        et[3] = (du / dy + dv / dx) * 0.5f;
        et[4] = (du / dz + dw / dx) * 0.5f;
        et[5] = (dw / dy + dv / dz) * 0.5f;

        #pragma unroll
        for (int a = 0; a < 6; ++a) {
            float s2 = 0.0f;
            #pragma unroll
            for (int b2 = 0; b2 < 6; ++b2) s2 += C.c[a][b2] * et[b2];
            q += et[a] * s2;
        }
    }

    // block reduction: wave shuffle + LDS handoff (unchanged order)
    double q2 = (double)q * (double)q;
    #pragma unroll
    for (int off = 32; off > 0; off >>= 1)
        q2 += __shfl_down(q2, off, 64);
    const ull vm = __ballot(valid);
    const int lane = tid & 63;
    const int wid = tid >> 6;

    __shared__ double wsum[4];
    __shared__ unsigned wcnt2[4];
    __shared__ bool sdone;
    if (lane == 0) { wsum[wid] = q2; wcnt2[wid] = (unsigned)__popcll(vm); }
    __syncthreads();
    if (tid == 0) {
        partial_sum[f] = wsum[0] + wsum[1] + wsum[2] + wsum[3];
        partial_cnt[f] = wcnt2[0] + wcnt2[1] + wcnt2[2] + wcnt2[3];
        __threadfence();                      // release partials device-wide
        const unsigned t = atomicAdd(ticket3, 1u);
        sdone = (t == NPART - 1);             // last block finalizes
    }
    __syncthreads();

    if (sdone && tid < 64) {
        __threadfence();                      // acquire side
        double ss = (tid < NPART) ? partial_sum[tid] : 0.0;
        double cc2 = (tid < NPART) ? (double)partial_cnt[tid] : 0.0;
        #pragma unroll
        for (int off = 32; off > 0; off >>= 1) {
            ss += __shfl_down(ss, off, 64);
            cc2 += __shfl_down(cc2, off, 64);
        }
        if (tid == 0) out[0] = (float)(sqrt(ss) / cc2);
    }
}

// ---------------- Host: build C = inv(Ci) -----------------------------------
static void build_cmat(CMat* M)
{
    const double VP = 0.4, EP = 0.21;
    double A[6][12];
    memset(A, 0, sizeof(A));
    double Ci[6][6];
    memset(Ci, 0, sizeof(Ci));
    Ci[0][0] = 1.0 / EP; Ci[0][1] = -VP / EP; Ci[0][2] = -VP / EP;
    Ci[1][0] = -VP / EP; Ci[1][1] = 1.0 / EP; Ci[1][2] = -VP / EP;
    Ci[2][0] = -VP;      Ci[2][1] = -VP;      Ci[2][2] = 1.0 / EP;
    Ci[3][3] = 2.0 * (1.0 + VP) / EP;
    Ci[4][4] = Ci[3][3];
    Ci[5][5] = Ci[3][3];

    for (int i = 0; i < 6; ++i) {
        for (int j = 0; j < 6; ++j) A[i][j] = Ci[i][j];
        A[i][6 + i] = 1.0;
    }
    for (int col = 0; col < 6; ++col) {
        int piv = col;
        for (int r = col + 1; r < 6; ++r)
            if (fabs(A[r][col]) > fabs(A[piv][col])) piv = r;
        if (piv != col)
            for (int c = 0; c < 12; ++c) { double t = A[col][c]; A[col][c] = A[piv][c]; A[piv][c] = t; }
        const double d = A[col][col];
        for (int c = 0; c < 12; ++c) A[col][c] /= d;
        for (int r = 0; r < 6; ++r) {
            if (r == col) continue;
            const double f = A[r][col];
            if (f == 0.0) continue;
            for (int c = 0; c < 12; ++c) A[r][c] -= f * A[col][c];
        }
    }
    for (int i = 0; i < 6; ++i)
        for (int j = 0; j < 6; ++j)
            M->c[i][j] = (float)A[i][6 + j];
}

extern "C" void kernel_launch(void* const* d_in, const int* in_sizes, int n_in,
                              void* d_out, int out_size, void* d_ws, size_t ws_size,
                              hipStream_t stream)
{
    const float* new_xyz = (const float*)d_in[0];
    const float* xyz     = (const float*)d_in[1];
    const float* gt_sdf  = (const float*)d_in[2];
    float* out = (float*)d_out;

    // workspace layout (all consumed slots written before read):
    //   [0,      QP*16) : pts  float4 compacted inside points   (112 KB)
    //   [+,      QP*4)  : cj   original indices                 (28 KB)
    //   [+,      16)    : M    compact count
    //   [+,      QP*8)  : best u64 per-query NN minimum         (56 KB)
    //   then NPART doubles + NPART uints + 2 uint tickets
    char* p = (char*)d_ws;
    float4* pts = (float4*)p;                    p += (size_t)QP * 16;
    int* cj = (int*)p;                           p += (size_t)QP * 4;
    int* Mptr = (int*)p;                         p += 16;
    ull* best = (ull*)p;                         p += (size_t)QP * 8;
    double* partial_sum = (double*)p;            p += NPART * sizeof(double);
    unsigned int* partial_cnt = (unsigned int*)p; p += NPART * sizeof(unsigned int);
    unsigned int* ticket2 = (unsigned int*)p;    p += sizeof(unsigned int);
    unsigned int* ticket3 = (unsigned int*)p;

    CMat C;
    build_cmat(&C);

    build_kernel<<<BB, BT, 0, stream>>>(new_xyz, gt_sdf, pts, cj, Mptr, best,
                                        ticket2, ticket3);
    nn_loss_kernel<<<NBLK, 256, 0, stream>>>(new_xyz, xyz, pts, cj, Mptr, best,
                                             ticket2, ticket3,
                                             partial_sum, partial_cnt, out, C);
}

// Round 6
// 91.995 us; speedup vs baseline: 3.6123x; 1.0202x over previous
//
#include <hip/hip_runtime.h>
#include <math.h>
#include <string.h>

#define N 12288
#define QP 7168           // padded compact count = 56*128
#define TILE 128          // candidates per split (LDS tile)
#define NSPLIT 56         // QP / TILE
#define ACCS 2            // queries per thread
#define QBLK 512          // queries per block
#define NQB 14            // QP / QBLK
#define NBLK (NQB * NSPLIT) // 784 nn blocks
#define SCAN_R (N / 256)  // 48 scan rounds of 256 threads
#define NPART (QP / 256)  // 28 loss blocks

typedef unsigned long long ull;

struct CMat { float c[6][6]; };

// ---------------------------------------------------------------------------
// Redundant in-block compaction scan (256 threads):
//   flags[r] = inside(element r*256+tid); per-(round,wave) ballot counts ->
//   192-entry exclusive prefix via wave shuffle-scan; compact slot of element
//   (r,w,lane) = spref[r*4+w] + rank-in-ballot. Order (r,w,lane) == ascending
//   original index => identical compaction to all previous builds.
// Every block recomputes this (~49 KB L2-broadcast reads + ~300 VALU) instead
// of a producer kernel: removes the build dispatch AND the best[]-init
// dependency (cross-XCD in-kernel barriers measured 2-3x a dispatch boundary
// in rounds 4/5 -- avoided entirely).
// ---------------------------------------------------------------------------
__device__ __forceinline__ void scan_flags(
    const float* __restrict__ gt_sdf, int tid, int lane, int w4,
    ull* flags_out, int* spref /*LDS[192]*/, int* scratch4 /*LDS[4]*/,
    int* M_out)
{
    ull flags = 0;
    #pragma unroll 8
    for (int r = 0; r < SCAN_R; ++r)
        if (gt_sdf[r * 256 + tid] < 1e-8f) flags |= (1ull << r);

    // per-(round,wave) counts into spref (reused as scnt first)
    #pragma unroll 8
    for (int r = 0; r < SCAN_R; ++r) {
        const ull m = __ballot((unsigned)((flags >> r) & 1ull));
        if (lane == 0) spref[r * 4 + w4] = __popcll(m);
    }
    __syncthreads();

    // exclusive scan of 192 counts: wave shuffle inclusive scan + wave offsets
    const int c = (tid < SCAN_R * 4) ? spref[tid] : 0;
    int inc = c;
    #pragma unroll
    for (int off = 1; off < 64; off <<= 1) {
        const int v = __shfl_up(inc, off, 64);
        if (lane >= off) inc += v;
    }
    if (lane == 63) scratch4[w4] = inc;
    __syncthreads();
    int wofs = 0;
    for (int w = 0; w < w4; ++w) wofs += scratch4[w];
    const int excl = wofs + inc - c;
    const int Mtot = scratch4[0] + scratch4[1] + scratch4[2] + scratch4[3];
    __syncthreads();                   // done reading scnt values
    if (tid < SCAN_R * 4) spref[tid] = excl;
    __syncthreads();

    *flags_out = flags;
    *M_out = Mtot;
}

// ---------------------------------------------------------------------------
// Kernel 1: NN with in-block compaction. Block f -> (qb=f%14, s=f/14).
// After the scan, the rewalk loads coords ONLY for compact slots inside
// [qbase,qbase+512) (queries, raw x/y/z; == -0.5*(-2x) of old path exactly)
// or [jb,jb+128) (tile, (-2x,-2y,-2z,x^2+y^2+z^2) with identical expression
// order; sentinel (0,0,0,3e30) beyond M). nn_inner unchanged (fma z,y,x,
// strict < over ascending k). Output: packed[s*QP+ci] plain stores
// (round-1 scheme: no init required). Blocks with jb>=M or qbase>=M exit
// (their rows/splits are never consumed). Block 0 zeroes ticket3 for K2.
// ---------------------------------------------------------------------------
template<bool CAREFUL>
__device__ __forceinline__ void nn_inner(
    const float4* __restrict__ tile,
    const float* wx, const float* wy, const float* wz,
    const int* kx,
    float* bd, int* bk)
{
    #pragma unroll 8
    for (int k = 0; k < TILE; ++k) {
        const float4 b = tile[k];
        #pragma unroll
        for (int a = 0; a < ACCS; ++a) {
            float t = fmaf(wz[a], b.z, b.w);
            t = fmaf(wy[a], b.y, t);
            t = fmaf(wx[a], b.x, t);
            bool ok = t < bd[a];
            if (CAREFUL) ok = ok && (k != kx[a]);
            if (ok) { bd[a] = t; bk[a] = k; }
        }
    }
}

__global__ __launch_bounds__(256, 4) void nn_pack_kernel(
    const float* __restrict__ new_xyz,
    const float* __restrict__ gt_sdf,
    ull* __restrict__ packed,
    unsigned int* __restrict__ ticket3)
{
    const int tid = threadIdx.x;
    const int f = blockIdx.x;        // 0..783
    const int lane = tid & 63;
    const int w4 = tid >> 6;
    const int qb = f % NQB;
    const int s = f / NQB;
    const int qbase = qb * QBLK;
    const int jb = s * TILE;

    __shared__ int spref[SCAN_R * 4];
    __shared__ int scratch4[4];
    __shared__ float qx[QBLK], qy[QBLK], qz[QBLK];
    __shared__ float4 tile[TILE];

    ull flags;
    int M;
    scan_flags(gt_sdf, tid, lane, w4, &flags, spref, scratch4, &M);

    if (f == 0 && tid == 0) *ticket3 = 0u;   // boundary makes this visible to K2

    if (jb >= M || qbase >= M) return;       // block-uniform skip

    // sentinel pre-fill (slots >= M keep these, matching old sentinel pts)
    for (int t = tid; t < QBLK; t += 256) { qx[t] = 0.0f; qy[t] = 0.0f; qz[t] = 0.0f; }
    if (tid < TILE) tile[tid] = make_float4(0.0f, 0.0f, 0.0f, 3e30f);
    __syncthreads();

    // rewalk: place owned inside elements that land in our ranges
    for (int r = 0; r < SCAN_R; ++r) {
        const ull m = __ballot((unsigned)((flags >> r) & 1ull));
        if ((flags >> r) & 1ull) {
            const int rank = __popcll(m & ((1ull << lane) - 1ull));
            const int slot = spref[r * 4 + w4] + rank;
            const bool inq = (slot >= qbase) && (slot < qbase + QBLK);
            const bool intl = (slot >= jb) && (slot < jb + TILE);
            if (inq || intl) {
                const int idx = r * 256 + tid;
                const float x = new_xyz[3 * idx + 0];
                const float y = new_xyz[3 * idx + 1];
                const float z = new_xyz[3 * idx + 2];
                if (inq) { qx[slot - qbase] = x; qy[slot - qbase] = y; qz[slot - qbase] = z; }
                if (intl) tile[slot - jb] = make_float4(-2.0f * x, -2.0f * y, -2.0f * z,
                                                        x * x + y * y + z * z);
            }
        }
    }
    __syncthreads();

    float wx[ACCS], wy[ACCS], wz[ACCS];
    int kx[ACCS];
    #pragma unroll
    for (int a = 0; a < ACCS; ++a) {
        const int t = tid + a * 256;
        wx[a] = qx[t];                 // == -0.5f*(-2.0f*x) bitwise
        wy[a] = qy[t];
        wz[a] = qz[t];
        kx[a] = qbase + t - jb;        // self position within this split
    }

    float bd[ACCS];
    int bk[ACCS];
    #pragma unroll
    for (int a = 0; a < ACCS; ++a) { bd[a] = 3.0e38f; bk[a] = 0; }

    const bool dirty = (jb < qbase + QBLK) && (jb + TILE > qbase);
    if (dirty)
        nn_inner<true>(tile, wx, wy, wz, kx, bd, bk);
    else
        nn_inner<false>(tile, wx, wy, wz, kx, bd, bk);

    #pragma unroll
    for (int a = 0; a < ACCS; ++a) {
        const int ci = qbase + tid + a * 256;
        unsigned u = __float_as_uint(bd[a]);
        u = ((int)u < 0) ? ~u : (u | 0x80000000u);
        packed[(size_t)s * QP + ci] = ((ull)u << 32) | (ull)(unsigned)(jb + bk[a]);
    }
}

// ---------------------------------------------------------------------------
// Kernel 2: loss. 28 blocks. Same scan -> full cj mapping in LDS (28 KB) +
// M. Combine = min over splits s < ceil(M/128) of packed[s*QP+ci] (identical
// candidate set to round 3's atomicMin; u64 min resolves ties to smallest j).
// Strain quadratic form + 28-partial reduction + ticket3 last-block finalize
// all verbatim from round 3 => bit-identical output.
// ---------------------------------------------------------------------------
__global__ __launch_bounds__(256) void loss_kernel(
    const float* __restrict__ new_xyz,
    const float* __restrict__ xyz,
    const float* __restrict__ gt_sdf,
    const ull* __restrict__ packed,
    double* __restrict__ partial_sum,
    unsigned int* __restrict__ partial_cnt,
    unsigned int* __restrict__ ticket3,
    float* __restrict__ out,
    CMat C)
{
    const int tid = threadIdx.x;
    const int f = blockIdx.x;        // 0..27
    const int lane = tid & 63;
    const int w4 = tid >> 6;

    __shared__ int spref[SCAN_R * 4];
    __shared__ int scratch4[4];
    __shared__ int cj_lds[QP];       // 28 KB

    ull flags;
    int M;
    scan_flags(gt_sdf, tid, lane, w4, &flags, spref, scratch4, &M);

    // rewalk: full cj mapping
    for (int r = 0; r < SCAN_R; ++r) {
        const ull m = __ballot((unsigned)((flags >> r) & 1ull));
        if ((flags >> r) & 1ull) {
            const int rank = __popcll(m & ((1ull << lane) - 1ull));
            const int slot = spref[r * 4 + w4] + rank;
            if (slot < QP) cj_lds[slot] = r * 256 + tid;
        }
    }
    __syncthreads();

    const int ns_eff = (M + TILE - 1) / TILE > NSPLIT ? NSPLIT : (M + TILE - 1) / TILE;
    const int ci = f * 256 + tid;

    ull best = ~0ull;
    #pragma unroll 8
    for (int s2 = 0; s2 < ns_eff; ++s2) {
        const ull p = packed[(size_t)s2 * QP + ci];
        best = (p < best) ? p : best;
    }

    const bool real = (ci < M);
    const unsigned u = (unsigned)(best >> 32);
    const unsigned bits = (u & 0x80000000u) ? (u ^ 0x80000000u) : ~u;
    const float key = __uint_as_float(bits);   // min (sqj - 2*dot)
    const int cc = real ? (int)(unsigned)(best & 0xffffffffu) : 0;

    const int i  = real ? cj_lds[ci] : 0;
    const int nn = cj_lds[cc];

    const float wix = new_xyz[3 * i + 0];
    const float wiy = new_xyz[3 * i + 1];
    const float wiz = new_xyz[3 * i + 2];
    const float sqi = wix * wix + wiy * wiy + wiz * wiz;

    const float d2 = sqi + key;
    const float nnd = sqrtf(fmaxf(d2, 0.0f));
    const bool valid = real && (nnd > 1e-8f);

    float q = 0.0f;
    if (valid) {
        const float xix = xyz[3 * i + 0], xiy = xyz[3 * i + 1], xiz = xyz[3 * i + 2];
        const float wnx = new_xyz[3 * nn + 0], wny = new_xyz[3 * nn + 1], wnz = new_xyz[3 * nn + 2];
        const float xnx = xyz[3 * nn + 0],     xny = xyz[3 * nn + 1],     xnz = xyz[3 * nn + 2];

        const float du = (wnx - xnx) - (wix - xix);
        const float dv = (wny - xny) - (wiy - xiy);
        const float dw = (wnz - xnz) - (wiz - xiz);
        const float dx = wnx - wix + 1e-8f;
        const float dy = wny - wiy + 1e-8f;
        const float dz = wnz - wiz + 1e-8f;

        float et[6];
        et[0] = du / dx;
        et[1] = dv / dy;
        et[2] = dw / dz;
        et[3] = (du / dy + dv / dx) * 0.5f;
        et[4] = (du / dz + dw / dx) * 0.5f;
        et[5] = (dw / dy + dv / dz) * 0.5f;

        #pragma unroll
        for (int a = 0; a < 6; ++a) {
            float s2 = 0.0f;
            #pragma unroll
            for (int b2 = 0; b2 < 6; ++b2) s2 += C.c[a][b2] * et[b2];
            q += et[a] * s2;
        }
    }

    // block reduction: wave shuffle + LDS handoff (unchanged order)
    double q2 = (double)q * (double)q;
    #pragma unroll
    for (int off = 32; off > 0; off >>= 1)
        q2 += __shfl_down(q2, off, 64);
    const ull vm = __ballot(valid);

    __shared__ double wsum[4];
    __shared__ unsigned wcnt2[4];
    __shared__ bool sdone;
    if (lane == 0) { wsum[w4] = q2; wcnt2[w4] = (unsigned)__popcll(vm); }
    __syncthreads();
    if (tid == 0) {
        partial_sum[f] = wsum[0] + wsum[1] + wsum[2] + wsum[3];
        partial_cnt[f] = wcnt2[0] + wcnt2[1] + wcnt2[2] + wcnt2[3];
        __threadfence();                      // release partials device-wide
        const unsigned t = atomicAdd(ticket3, 1u);
        sdone = (t == NPART - 1);             // last block finalizes
    }
    __syncthreads();

    if (sdone && tid < 64) {
        __threadfence();                      // acquire side
        double ss = (tid < NPART) ? partial_sum[tid] : 0.0;
        double cc2 = (tid < NPART) ? (double)partial_cnt[tid] : 0.0;
        #pragma unroll
        for (int off = 32; off > 0; off >>= 1) {
            ss += __shfl_down(ss, off, 64);
            cc2 += __shfl_down(cc2, off, 64);
        }
        if (tid == 0) out[0] = (float)(sqrt(ss) / cc2);
    }
}

// ---------------- Host: build C = inv(Ci) -----------------------------------
static void build_cmat(CMat* M)
{
    const double VP = 0.4, EP = 0.21;
    double A[6][12];
    memset(A, 0, sizeof(A));
    double Ci[6][6];
    memset(Ci, 0, sizeof(Ci));
    Ci[0][0] = 1.0 / EP; Ci[0][1] = -VP / EP; Ci[0][2] = -VP / EP;
    Ci[1][0] = -VP / EP; Ci[1][1] = 1.0 / EP; Ci[1][2] = -VP / EP;
    Ci[2][0] = -VP;      Ci[2][1] = -VP;      Ci[2][2] = 1.0 / EP;
    Ci[3][3] = 2.0 * (1.0 + VP) / EP;
    Ci[4][4] = Ci[3][3];
    Ci[5][5] = Ci[3][3];

    for (int i = 0; i < 6; ++i) {
        for (int j = 0; j < 6; ++j) A[i][j] = Ci[i][j];
        A[i][6 + i] = 1.0;
    }
    for (int col = 0; col < 6; ++col) {
        int piv = col;
        for (int r = col + 1; r < 6; ++r)
            if (fabs(A[r][col]) > fabs(A[piv][col])) piv = r;
        if (piv != col)
            for (int c = 0; c < 12; ++c) { double t = A[col][c]; A[col][c] = A[piv][c]; A[piv][c] = t; }
        const double d = A[col][col];
        for (int c = 0; c < 12; ++c) A[col][c] /= d;
        for (int r = 0; r < 6; ++r) {
            if (r == col) continue;
            const double fc = A[r][col];
            if (fc == 0.0) continue;
            for (int c = 0; c < 12; ++c) A[r][c] -= fc * A[col][c];
        }
    }
    for (int i = 0; i < 6; ++i)
        for (int j = 0; j < 6; ++j)
            M->c[i][j] = (float)A[i][6 + j];
}

extern "C" void kernel_launch(void* const* d_in, const int* in_sizes, int n_in,
                              void* d_out, int out_size, void* d_ws, size_t ws_size,
                              hipStream_t stream)
{
    const float* new_xyz = (const float*)d_in[0];
    const float* xyz     = (const float*)d_in[1];
    const float* gt_sdf  = (const float*)d_in[2];
    float* out = (float*)d_out;

    // workspace layout:
    //   [0, NSPLIT*QP*8) : packed u64 per (split, ci)  (3.2 MB)
    //   then NPART doubles + NPART uints + 1 uint ticket
    char* p = (char*)d_ws;
    ull* packed = (ull*)p;                        p += (size_t)NSPLIT * QP * 8;
    double* partial_sum = (double*)p;             p += NPART * sizeof(double);
    unsigned int* partial_cnt = (unsigned int*)p; p += NPART * sizeof(unsigned int);
    unsigned int* ticket3 = (unsigned int*)p;

    CMat C;
    build_cmat(&C);

    nn_pack_kernel<<<NBLK, 256, 0, stream>>>(new_xyz, gt_sdf, packed, ticket3);
    loss_kernel<<<NPART, 256, 0, stream>>>(new_xyz, xyz, gt_sdf, packed,
                                           partial_sum, partial_cnt, ticket3,
                                           out, C);
}